// Round 1
// baseline (927.434 us; speedup 1.0000x reference)
//
#include <hip/hip_runtime.h>

#define Bn   256
#define SEQn 196
#define Dn   768
#define Hn   12
#define DHn  64
#define L2n  24
#define POOLn 20
#define KSEL 4
#define LENn 5

// floats per pool row: LEN*H*DH
#define ROW_F 3840
#define ROW_V4 960
// floats per (l2,b) output segment: KSEL*ROW_F
#define SEG_F 15360
#define SEG_V4 3840

// s_batched total floats = L2*B*SEG_F
#define S_OUT_F 94371840LL
#define S_OUT_V4 23592960LL
#define REDUCE_OFF 188743680LL   // 2*S_OUT_F

// ---------------- Kernel 1: normalize the 40 key rows + zero reduce slots ----------------
__global__ __launch_bounds__(192) void knorm_keys(const float* __restrict__ skey,
                                                  const float* __restrict__ mkey,
                                                  float* __restrict__ skeyn,
                                                  float* __restrict__ mkeyn,
                                                  float* __restrict__ out) {
    int row = blockIdx.x;                 // 0..39
    const float* src = (row < POOLn) ? (skey + (size_t)row * Dn)
                                     : (mkey + (size_t)(row - POOLn) * Dn);
    float* dst = (row < POOLn) ? (skeyn + (size_t)row * Dn)
                               : (mkeyn + (size_t)(row - POOLn) * Dn);
    int t = threadIdx.x;                  // 192 threads, one float4 each (768/4)
    float4 v = ((const float4*)src)[t];
    float ss = v.x * v.x + v.y * v.y + v.z * v.z + v.w * v.w;
    for (int off = 32; off; off >>= 1) ss += __shfl_down(ss, off, 64);
    __shared__ float wss[3];
    int lane = t & 63, w = t >> 6;
    if (lane == 0) wss[w] = ss;
    __syncthreads();
    float tot = wss[0] + wss[1] + wss[2];
    float inv = rsqrtf(fmaxf(tot, 1e-12f));
    float4 o;
    o.x = v.x * inv; o.y = v.y * inv; o.z = v.z * inv; o.w = v.w * inv;
    ((float4*)dst)[t] = o;
    if (row == 0 && t < 2) out[REDUCE_OFF + t] = 0.0f;   // init before ksim's atomics
}

// ---------------- Kernel 2: x_mean over SEQ + L2 normalize ----------------
__global__ __launch_bounds__(192) void kxnorm(const float* __restrict__ x,
                                              float* __restrict__ xn) {
    int b = blockIdx.x;                    // 0..255
    int t = threadIdx.x;                   // 192 threads, one float4 column each
    const float4* src = (const float4*)(x + (size_t)b * SEQn * Dn);
    float4 acc = make_float4(0.f, 0.f, 0.f, 0.f);
    for (int s = 0; s < SEQn; ++s) {
        float4 v = src[(size_t)s * (Dn / 4) + t];
        acc.x += v.x; acc.y += v.y; acc.z += v.z; acc.w += v.w;
    }
    const float scale = 1.0f / (float)SEQn;
    acc.x *= scale; acc.y *= scale; acc.z *= scale; acc.w *= scale;
    float ss = acc.x * acc.x + acc.y * acc.y + acc.z * acc.z + acc.w * acc.w;
    for (int off = 32; off; off >>= 1) ss += __shfl_down(ss, off, 64);
    __shared__ float wss[3];
    int lane = t & 63, w = t >> 6;
    if (lane == 0) wss[w] = ss;
    __syncthreads();
    float tot = wss[0] + wss[1] + wss[2];
    float inv = rsqrtf(fmaxf(tot, 1e-12f));
    float4 o;
    o.x = acc.x * inv; o.y = acc.y * inv; o.z = acc.z * inv; o.w = acc.w * inv;
    ((float4*)(xn + (size_t)b * Dn))[t] = o;
}

// ---------------- Kernel 3: sims + top-4 + reduce sums ----------------
__global__ __launch_bounds__(256) void ksim(const float* __restrict__ xn,
                                            const float* __restrict__ skeyn,
                                            const float* __restrict__ mkeyn,
                                            int* __restrict__ sidx,
                                            int* __restrict__ midx,
                                            float* __restrict__ out) {
    int b = blockIdx.x;                    // 0..255
    int t = threadIdx.x;                   // 256 threads = 4 waves
    __shared__ float xs[Dn];
    __shared__ float sims[40];
    for (int i = t; i < Dn; i += 256) xs[i] = xn[(size_t)b * Dn + i];
    __syncthreads();
    int w = t >> 6, lane = t & 63;
    // 40 keys (20 s, 20 m); each wave handles 10
    for (int i = 0; i < 10; ++i) {
        int key = w * 10 + i;
        const float* kr = (key < POOLn) ? (skeyn + (size_t)key * Dn)
                                        : (mkeyn + (size_t)(key - POOLn) * Dn);
        float p = 0.f;
        for (int j = lane; j < Dn; j += 64) p += kr[j] * xs[j];
        for (int off = 32; off; off >>= 1) p += __shfl_down(p, off, 64);
        if (lane == 0) sims[key] = p;
    }
    __syncthreads();
    if (t < 2) {
        const float* sv = sims + t * POOLn;       // t==0 -> s, t==1 -> m
        int* idxout = (t == 0) ? sidx : midx;
        unsigned used = 0;
        float sum = 0.f;
        for (int k = 0; k < KSEL; ++k) {
            int best = -1; float bv = -3.0e38f;
            for (int p = 0; p < POOLn; ++p) {
                if (!((used >> p) & 1u) && sv[p] > bv) { bv = sv[p]; best = p; }
            }
            used |= 1u << best;
            idxout[b * KSEL + k] = best;
            sum += bv;
        }
        atomicAdd(&out[REDUCE_OFF + t], sum * (1.0f / (float)Bn));
    }
}

// ---------------- Kernel 4: the gather (write-BW bound) ----------------
__global__ __launch_bounds__(256) void kgather(const float* __restrict__ sp,
                                               const float* __restrict__ mp,
                                               const int* __restrict__ sidx,
                                               const int* __restrict__ midx,
                                               float* __restrict__ out) {
    int bid = blockIdx.x;                  // l2*B + b, 0..6143
    int l2 = bid >> 8;                     // B == 256
    int b = bid & 255;
    int t = threadIdx.x;                   // 256
    int si[KSEL], mi[KSEL];
#pragma unroll
    for (int k = 0; k < KSEL; ++k) {
        si[k] = sidx[b * KSEL + k];
        mi[k] = midx[b * KSEL + k];
    }
    const float4* sp4 = (const float4*)sp;
    const float4* mp4 = (const float4*)mp;
    float4* o4 = (float4*)out;
    size_t dbase = (size_t)bid * SEG_V4;
#pragma unroll
    for (int i = 0; i < 15; ++i) {         // 3840 float4 / 256 threads
        int tt = t + i * 256;
        int k = tt / ROW_V4;
        int j = tt - k * ROW_V4;
        o4[dbase + tt] = sp4[(size_t)(l2 * POOLn + si[k]) * ROW_V4 + j];
    }
    size_t mbase = S_OUT_V4 + dbase;
#pragma unroll
    for (int i = 0; i < 15; ++i) {
        int tt = t + i * 256;
        int k = tt / ROW_V4;
        int j = tt - k * ROW_V4;
        o4[mbase + tt] = mp4[(size_t)(l2 * POOLn + mi[k]) * ROW_V4 + j];
    }
}

extern "C" void kernel_launch(void* const* d_in, const int* in_sizes, int n_in,
                              void* d_out, int out_size, void* d_ws, size_t ws_size,
                              hipStream_t stream) {
    const float* x_embed = (const float*)d_in[0];   // [B, SEQ, D]
    const float* s_prompt = (const float*)d_in[1];  // [L2, 20, 5, 12, 64]
    const float* m_prompt = (const float*)d_in[2];  // [L2, 20, 5, 12, 64]
    const float* s_key = (const float*)d_in[3];     // [20, D]
    const float* m_key = (const float*)d_in[4];     // [20, D]
    float* out = (float*)d_out;

    // workspace layout (floats)
    float* ws = (float*)d_ws;
    float* xn = ws;                          // B*D = 196608
    float* skeyn = xn + (size_t)Bn * Dn;     // 15360
    float* mkeyn = skeyn + POOLn * Dn;       // 15360
    int* sidx = (int*)(mkeyn + POOLn * Dn);  // B*4 ints
    int* midx = sidx + Bn * KSEL;            // B*4 ints

    knorm_keys<<<40, 192, 0, stream>>>(s_key, m_key, skeyn, mkeyn, out);
    kxnorm<<<Bn, 192, 0, stream>>>(x_embed, xn);
    ksim<<<Bn, 256, 0, stream>>>(xn, skeyn, mkeyn, sidx, midx, out);
    kgather<<<L2n * Bn, 256, 0, stream>>>(s_prompt, m_prompt, sidx, midx, out);
}